// Round 5
// baseline (532.297 us; speedup 1.0000x reference)
//
#include <hip/hip_runtime.h>

// Problem constants (B=8, G=1024, K=32, C=168, OUT_DIM=336)
#define NGQ 1024
#define NKQ 32
#define NCQ 168
#define NOUTC 336
#define NXF 44040192       // B*G*K*C
#define NXYZQ 786432       // B*G*K*3
#define EPSV 1e-5f
#define PIO2 1.5707963267948966f
#define L2A_OVER_FD 0.17796043436f   // log2(1000)/56

#define NPART_X 1024
#define NPART_3 32
#define NPART (NPART_X + NPART_3)

#define GRID2 2048         // main blocks; 4 tiles each (8192 = 2048*4)
#define TPB2 256
#define NTILE 8192         // B*G
#define TSTR 169           // padded c-stride per k-row (conflict-free phase-C reads)
#define TILEF (NKQ * TSTR) // 5408 floats

// ---------------- Pass 1: partial sums for the two global stds ----------------
// (verbatim from the harness-verified baseline)
__global__ __launch_bounds__(256) void reduce_kernel(
    const float* __restrict__ knn_x, const float* __restrict__ lc_x,
    const float* __restrict__ knn_xyz, const float* __restrict__ lc_xyz,
    float4* __restrict__ part)
{
    float s = 0.f, q = 0.f, s3 = 0.f, q3 = 0.f;
    const int blk = blockIdx.x;
    const int tid = threadIdx.x;

    if (blk < NPART_X) {
        const float4* __restrict__ x4 = (const float4*)knn_x;
        const int n4 = NXF / 4;                     // 11,010,048
        for (int i = blk * 256 + tid; i < n4; i += NPART_X * 256) {
            float4 v = x4[i];
            int bg  = i / 1344;
            int c4  = i - bg * 1344;
            int r42 = c4 % 42;
            float4 l = *(const float4*)(lc_x + (size_t)bg * NCQ + r42 * 4);
            float dx = v.x - l.x, dy = v.y - l.y, dz = v.z - l.z, dw = v.w - l.w;
            s += (dx + dy) + (dz + dw);
            q = fmaf(dx, dx, q); q = fmaf(dy, dy, q);
            q = fmaf(dz, dz, q); q = fmaf(dw, dw, q);
        }
    } else {
        for (int i = (blk - NPART_X) * 256 + tid; i < NXYZQ; i += NPART_3 * 256) {
            float v = knn_xyz[i];
            int bg = i / 96;
            int j  = i % 3;
            float d = v - lc_xyz[bg * 3 + j];
            s3 += d;
            q3 = fmaf(d, d, q3);
        }
    }

    for (int off = 32; off; off >>= 1) {
        s  += __shfl_down(s,  off);
        q  += __shfl_down(q,  off);
        s3 += __shfl_down(s3, off);
        q3 += __shfl_down(q3, off);
    }
    __shared__ float red[4][4];
    int wv = tid >> 6;
    if ((tid & 63) == 0) { red[wv][0] = s; red[wv][1] = q; red[wv][2] = s3; red[wv][3] = q3; }
    __syncthreads();
    if (tid == 0) {
        part[blk] = make_float4(red[0][0] + red[1][0] + red[2][0] + red[3][0],
                                red[0][1] + red[1][1] + red[2][1] + red[3][1],
                                red[0][2] + red[1][2] + red[2][2] + red[3][2],
                                red[0][3] + red[1][3] + red[2][3] + red[3][3]);
    }
}

// ---------------- Pass 2: redundant finalize + pipelined fused main ----------
// 2048 blocks x 256 threads, 4 tiles each. Per tile-step:
//   A: barrier (prev phase-C done, LDS free)
//   B: ds_write register-staged tile t (knn_x, knn_xyz, lc_xyz)
//   C: barrier (LDS ready)
//   D: issue register prefetch of tile t+1  (lands under phase C — async split)
//   E: geometry + per-channel consts (pure LDS/VALU, no global loads)
//   F: barrier
//   G: phase C — plain (non-NT) coalesced stores, 128B/half-wave chunks
__global__ __launch_bounds__(TPB2) void main_kernel(
    const float* __restrict__ lc_xyz, const float* __restrict__ lc_x,
    const float* __restrict__ knn_xyz, const float* __restrict__ knn_x,
    const float4* __restrict__ part, float* __restrict__ out)
{
    __shared__ float  s_x[TILEF];        // 21,632 B raw knn_x tile (169-pad)
    __shared__ float4 s_cc[NOUTC];       //  5,376 B {scale, phase, pe_lc, lc_x}
    __shared__ float2 s_so[NOUTC];       //  2,688 B {scale, off} (tile-invariant)
    __shared__ float  s_emb[NKQ * 7];    //    896 B per-k {xn0..2, cross, dot}
    __shared__ float  s_kxyz[NKQ * 3];   //    384 B
    __shared__ float  s_lc[3];
    __shared__ double redd[4][4];
    __shared__ float  s_inv[2];

    const int tid = threadIdx.x;
    const int wv  = tid >> 6;

    // ---- redundant finalize (identical order in every block => deterministic)
    {
        double sd = 0.0, qd = 0.0, s3d = 0.0, q3d = 0.0;
        for (int i = tid; i < NPART; i += TPB2) {
            float4 p = part[i];
            sd += p.x; qd += p.y; s3d += p.z; q3d += p.w;
        }
        for (int off = 32; off; off >>= 1) {
            sd  += __shfl_down(sd,  off);  qd  += __shfl_down(qd,  off);
            s3d += __shfl_down(s3d, off);  q3d += __shfl_down(q3d, off);
        }
        if ((tid & 63) == 0) { redd[wv][0]=sd; redd[wv][1]=qd; redd[wv][2]=s3d; redd[wv][3]=q3d; }
        __syncthreads();
        if (tid == 0) {
            double S=0,Q=0,S3=0,Q3=0;
            for (int w = 0; w < 4; ++w) { S+=redd[w][0]; Q+=redd[w][1]; S3+=redd[w][2]; Q3+=redd[w][3]; }
            double varx = (Q  - S  * S  / (double)NXF)   / (double)(NXF - 1);
            double var3 = (Q3 - S3 * S3 / (double)NXYZQ) / (double)(NXYZQ - 1);
            s_inv[0] = 1.0f / ((float)sqrt(varx) + EPSV);
            s_inv[1] = 1.0f / ((float)sqrt(var3) + EPSV);
        }
    }
    for (int c = tid; c < NOUTC; c += TPB2) {   // tile-invariant {scale, off}
        int dq = c / 112;
        int r  = c - dq * 112;
        int sf = (r >= 56);
        int f  = sf ? r - 56 : r;
        float scale = 100.f * exp2f(-L2A_OVER_FD * (float)f);  // 100/alpha^(f/56)
        s_so[c] = make_float2(scale, sf ? PIO2 : 0.f);         // cos = sin(+pi/2)
    }
    __syncthreads();
    const float inv_sx = s_inv[0];
    const float inv_s3 = s_inv[1];

    // ---- register prefetch state ----
    float4 pf[6];
    float  pf_kx = 0.f, pf_lcx = 0.f, pf_lx = 0.f;
    int t = blockIdx.x;

    // prologue: prefetch tile 0 of this block
    {
        const float4* __restrict__ s4 = (const float4*)knn_x + (size_t)t * 1344;
        #pragma unroll
        for (int j = 0; j < 5; ++j) pf[j] = s4[tid + 256 * j];
        if (tid < 64)  pf[5]  = s4[tid + 1280];
        if (tid < 96)  pf_kx  = knn_xyz[(size_t)t * 96 + tid];
        if (tid < 3)   pf_lcx = lc_xyz[(size_t)t * 3 + tid];
        if (tid < NCQ) pf_lx  = lc_x[(size_t)t * NCQ + tid];
    }

    const int c0 = tid >> 5;                  // 0..7: channel phase
    const int k  = tid & 31;
    const size_t STEPF = (size_t)8 << 15;     // 8 c-planes in floats

    for (int it = 0; it < 4; ++it) {
        const int tile = t;
        const int tn   = t + GRID2;

        __syncthreads();                      // A: prev phase C done
        // B: ds_write the register-staged tile
        #pragma unroll
        for (int j = 0; j < 6; ++j) {
            if (j < 5 || tid < 64) {
                int i  = tid + 256 * j;
                int kk = i / 42;
                int c4 = i - kk * 42;
                float* dst = s_x + kk * TSTR + c4 * 4;
                float4 v = pf[j];
                dst[0]=v.x; dst[1]=v.y; dst[2]=v.z; dst[3]=v.w;
            }
        }
        if (tid < 96) s_kxyz[tid] = pf_kx;
        if (tid < 3)  s_lc[tid]  = pf_lcx;
        const float lxv = pf_lx;              // consumed by consts (same thread)
        __syncthreads();                      // C: LDS staged

        // D: issue prefetch of next tile (no wait — lands under E+F+G)
        if (it < 3) {
            const float4* __restrict__ s4 = (const float4*)knn_x + (size_t)tn * 1344;
            #pragma unroll
            for (int j = 0; j < 5; ++j) pf[j] = s4[tid + 256 * j];
            if (tid < 64)  pf[5]  = s4[tid + 1280];
            if (tid < 96)  pf_kx  = knn_xyz[(size_t)tn * 96 + tid];
            if (tid < 3)   pf_lcx = lc_xyz[(size_t)tn * 3 + tid];
            if (tid < NCQ) pf_lx  = lc_x[(size_t)tn * NCQ + tid];
        }

        // E: geometry + per-channel constants (pure LDS/VALU)
        const float b0 = s_lc[0], b1 = s_lc[1], b2 = s_lc[2];
        if (tid < NKQ) {
            float a0 = (s_kxyz[tid*3+0] - b0) * inv_s3;
            float a1 = (s_kxyz[tid*3+1] - b1) * inv_s3;
            float a2 = (s_kxyz[tid*3+2] - b2) * inv_s3;
            float* e = s_emb + tid * 7;
            e[0]=a0; e[1]=a1; e[2]=a2;
            e[3]=a1*b2 - a2*b1;               // cross(knn_xyz_n, lc)
            e[4]=a2*b0 - a0*b2;
            e[5]=a0*b1 - a1*b0;
            e[6]=a0*b0 + a1*b1 + a2*b2;       // dot
        }
        for (int c = tid; c < NOUTC; c += TPB2) {
            float2 so = s_so[c];
            int dq = c / 112;
            float lcv  = (dq == 0) ? b0 : (dq == 1 ? b1 : b2);
            float pelc = __sinf(fmaf(lcv, so.x, so.y));
            float lx   = (c < NCQ) ? lxv : 0.f;   // c==tid when c<168
            s_cc[c] = make_float4(so.x, so.y, pelc, lx);
        }
        __syncthreads();                      // F: s_emb/s_cc ready

        // G: phase C — half-wave = one c-plane x 32k = 128B contiguous store
        const float* sx = s_x + k * TSTR;
        const float* se = s_emb + k * 7;
        const float xn0 = se[0], xn1 = se[1], xn2 = se[2];
        float* op = out + (size_t)(tile >> 10) * ((size_t)NOUTC << 15)
                        + ((size_t)(tile & 1023) << 5) + k + ((size_t)c0 << 15);
        int c = c0;

#define BODY(WEXPR, TT) do { float4 cc = s_cc[c]; float w = (WEXPR); \
        float pe = __sinf(fmaf((TT), cc.x, cc.y)) + cc.z; \
        *op = (w + pe) * pe; op += STEPF; c += 8; } while (0)

        // c = c0+8j: j<14 -> c<112 ; j<21 -> c<168 ; j<28 -> c<224 (branch-free)
        #pragma unroll
        for (int j = 0; j < 14; ++j) BODY((sx[c] - cc.w) * inv_sx, xn0);
        #pragma unroll
        for (int j = 0; j < 7;  ++j) BODY((sx[c] - cc.w) * inv_sx, xn1);
        int e7 = (c0 >= 7) ? c0 - 7 : c0;     // (c-168)%7; step 8 == +1 mod 7
        #pragma unroll
        for (int j = 0; j < 7;  ++j) { BODY(se[e7], xn1); e7 = (e7 == 6) ? 0 : e7 + 1; }
        #pragma unroll
        for (int j = 0; j < 14; ++j) { BODY(se[e7], xn2); e7 = (e7 == 6) ? 0 : e7 + 1; }
#undef BODY

        t = tn;
    }
}

extern "C" void kernel_launch(void* const* d_in, const int* in_sizes, int n_in,
                              void* d_out, int out_size, void* d_ws, size_t ws_size,
                              hipStream_t stream) {
    const float* lc_xyz  = (const float*)d_in[0];
    const float* lc_x    = (const float*)d_in[1];
    const float* knn_xyz = (const float*)d_in[2];
    const float* knn_x   = (const float*)d_in[3];
    float* outp  = (float*)d_out;
    float4* part = (float4*)d_ws;             // NPART*16 B = 16.9 KB of workspace

    reduce_kernel<<<NPART, 256, 0, stream>>>(knn_x, lc_x, knn_xyz, lc_xyz, part);
    main_kernel<<<GRID2, TPB2, 0, stream>>>(lc_xyz, lc_x, knn_xyz, knn_x, part, outp);
}